// Round 3
// baseline (161.686 us; speedup 1.0000x reference)
//
#include <hip/hip_runtime.h>
#include <hip/hip_bf16.h>
#include <stdint.h>

typedef __bf16 bf16x8 __attribute__((ext_vector_type(8)));
typedef float  f32x4  __attribute__((ext_vector_type(4)));

#define NROWS   8192
#define DIMK    128
#define RECON_N 6422528
#define NTOT4   1605632              // xrecon float4 count = 8192*784/4
#define GRID    1024                 // 4 blocks/CU x 256 CU, all co-resident
#define NTILES  2080                 // upper-tri 64x64 grid of 128x128 tiles

// workspace layout (float offsets)
#define WS_RS     0                  // rowSum[8192], atomic-accumulated
#define WS_G      8192
#define WS_E      16384
#define WS_RPART  24576              // 1024 recon partials
#define WS_DPART  25600              // 512 group partials
#define WS_PB     26112              // byte 104448 (16B aligned); bf16 P, 2MB

__device__ __forceinline__ void async16(const void* g, void* l) {
    __builtin_amdgcn_global_load_lds(
        (const __attribute__((address_space(1))) void*)g,
        (__attribute__((address_space(3))) void*)l, 16, 0, 0);
}

__device__ __forceinline__ unsigned short f2bf(float f) {
    union { __hip_bfloat16 h; unsigned short u; } v;
    v.h = __float2bfloat16(f);
    return v.u;
}

// decode linear tile id u -> (I,J) upper triangle
__device__ __forceinline__ void decodeIJ(int u, int& I, int& J) {
    float ff = 64.5f - sqrtf(64.5f * 64.5f - 2.0f * (float)u);
    I = (int)ff;
    int base = I * 64 - (I * (I - 1)) / 2;
    if (u < base) { --I; base = I * 64 - (I * (I - 1)) / 2; }
    else { int nb = (I + 1) * 64 - ((I + 1) * I) / 2;
           if (u >= nb) { ++I; base = nb; } }
    J = I + (u - base);
}

__device__ __forceinline__ void stageJ(const unsigned short* Pb, int J,
                                       unsigned short* tile, int wave, int lane) {
    const char* gB = (const char*)(Pb + (size_t)J * 128 * DIMK);
#pragma unroll
    for (int i = 0; i < 8; ++i) {
        int chunk = i * 256 + wave * 64 + lane;      // 2048 x 16B
        int r = chunk >> 4, qp = chunk & 15;
        async16(gB + r * 256 + (((qp - r) & 15) << 4),
                (char*)tile + chunk * 16);
    }
}

// -------- k1: convert P fp32 -> bf16; zero rowSum --------
__global__ __launch_bounds__(256) void prep_kernel(const float4* __restrict__ Pf,
                                                   uint2* __restrict__ Pb,
                                                   float* __restrict__ ws) {
    int idx = blockIdx.x * 256 + threadIdx.x;    // 262144 float4s
    if (blockIdx.x < 32) ws[WS_RS + idx] = 0.f;  // rowSum[8192] = 0
    float4 a = Pf[idx];
    uint2 r;
    r.x = (uint32_t)f2bf(a.x) | ((uint32_t)f2bf(a.y) << 16);
    r.y = (uint32_t)f2bf(a.z) | ((uint32_t)f2bf(a.w) << 16);
    Pb[idx] = r;
}

// -------- k2: persistent fused kernel: 1024 blocks, all co-resident --------
// Each block: 2-3 symmetric sim tiles (row+col sums via operand-swap symmetry),
// 7 recon rounds pipelined into the MFMA j-slots, group phase on blocks >=512.
__global__ __launch_bounds__(256, 4) void fused_kernel(
        const unsigned short* __restrict__ Pb,
        const float* __restrict__ Pf,
        const float4* __restrict__ X,
        const float4* __restrict__ Y,
        float* __restrict__ ws) {
    __shared__ unsigned short tile[128 * 128];   // 32 KB (sim B staging)
    __shared__ float sred[2][2][64];             // row partials [wc][wr][row]
    __shared__ float cred[2][128];               // col partials [wr][col]
    __shared__ float red[4];                     // recon partials
    __shared__ float dred[4];                    // group partials

    const int bid = blockIdx.x;
    const int wave = threadIdx.x >> 6, lane = threadIdx.x & 63;
    const int wr = wave >> 1, wc = wave & 1;
    const int m = lane & 15, kq = lane >> 4;
    float* RS = ws + WS_RS;

    // recon state: rounds k=0..6, i = k*262144 + gi; round 6 partial
    const int gi = bid * 256 + threadIdx.x;
    const bool has7 = gi < (NTOT4 - 6 * 262144);
    float rsum = 0.f;
    float4 rx0, ry0, rx1, ry1;

    // ---- prologue: stage first tile, issue recon round 0 ----
    {
        int I0, J0; decodeIJ(bid, I0, J0);
        stageJ(Pb, J0, tile, wave, lane);
    }
    rx0 = X[gi]; ry0 = Y[gi];                    // round 0 (always valid)
    __syncthreads();                             // drain stage(first)

    int u = bid, k0 = 0;
    while (u < NTILES) {
        int I, J; decodeIJ(u, I, J);

        // A fragments = I-block rows from global (L2-hot)
        bf16x8 Af[4][4];
        const unsigned short* gA = Pb + (size_t)(I * 128 + wr * 64) * DIMK;
#pragma unroll
        for (int i = 0; i < 4; ++i) {
            const unsigned short* rowp = gA + (size_t)(i * 16 + m) * DIMK + kq * 8;
#pragma unroll
            for (int kk = 0; kk < 4; ++kk)
                Af[i][kk] = *(const bf16x8*)(rowp + kk * 32);
        }

        float rowAcc[4][4];
        float colAcc[4];
#pragma unroll
        for (int i = 0; i < 4; ++i)
#pragma unroll
            for (int r = 0; r < 4; ++r) rowAcc[i][r] = 0.f;

#pragma unroll
        for (int j = 0; j < 4; ++j) {
            const int k = k0 + j;                // global slot id (even k0)
            // issue recon round k+1 one slot ahead; parity (k+1)&1 == (j&1)^1
            if (k < 6) {
                int rk = k + 1;
                int i1 = rk * 262144 + gi;
                bool use = (rk < 6) | has7;
                int ii = use ? i1 : gi;          // clamp to safe addr
                if (j & 1) { rx0 = X[ii]; ry0 = Y[ii]; }
                else       { rx1 = X[ii]; ry1 = Y[ii]; }
            }

            // ---- sim MFMA for 16-col group j ----
            int rl = wc * 64 + j * 16 + m;
            bf16x8 Bf[4];
#pragma unroll
            for (int kk = 0; kk < 4; ++kk)
                Bf[kk] = *(const bf16x8*)((const char*)tile + rl * 256 +
                                          (((kq + kk * 4 + rl) & 15) << 4));
            f32x4 acc[4];
#pragma unroll
            for (int i = 0; i < 4; ++i) acc[i] = (f32x4){0.f, 0.f, 0.f, 0.f};
#pragma unroll
            for (int kk = 0; kk < 4; ++kk)
#pragma unroll
                for (int i = 0; i < 4; ++i)
                    acc[i] = __builtin_amdgcn_mfma_f32_16x16x32_bf16(
                        Af[i][kk], Bf[kk], acc[i], 0, 0, 0);
            float cs = 0.f;
#pragma unroll
            for (int i = 0; i < 4; ++i)
#pragma unroll
                for (int r = 0; r < 4; ++r) {
                    float e = __builtin_amdgcn_exp2f(acc[i][r] * 14.426950408889634f);
                    rowAcc[i][r] += e;
                    cs += e;
                }
            cs += __shfl_xor(cs, 16, 64);        // sum over kq groups
            cs += __shfl_xor(cs, 32, 64);
            colAcc[j] = cs;

            // compute recon round k from set[k&1] == set[j&1]
            if (k <= 6) {
                bool use = (k < 6) | has7;
                float4 a = (j & 1) ? rx1 : rx0;
                float4 b = (j & 1) ? ry1 : ry0;
                float dx = use ? a.x - b.x : 0.f; rsum += dx * dx;
                float dy = use ? a.y - b.y : 0.f; rsum += dy * dy;
                float dz = use ? a.z - b.z : 0.f; rsum += dz * dz;
                float dw = use ? a.w - b.w : 0.f; rsum += dw * dw;
            }
        }

        __syncthreads();                         // all waves done reading tile
        int un = u + GRID;
        if (un < NTILES) {                       // stage next tile (safe now)
            int In, Jn; decodeIJ(un, In, Jn);
            stageJ(Pb, Jn, tile, wave, lane);
        }

        // ---- epilogue: row-sums (16-lane reduce) + write partials ----
#pragma unroll
        for (int i = 0; i < 4; ++i)
#pragma unroll
            for (int r = 0; r < 4; ++r) {
                float sv = rowAcc[i][r];
                sv += __shfl_xor(sv, 1, 64);
                sv += __shfl_xor(sv, 2, 64);
                sv += __shfl_xor(sv, 4, 64);
                sv += __shfl_xor(sv, 8, 64);
                rowAcc[i][r] = sv;
            }
        if (m == 0) {
#pragma unroll
            for (int i = 0; i < 4; ++i)
#pragma unroll
                for (int r = 0; r < 4; ++r)
                    sred[wc][wr][i * 16 + kq * 4 + r] = rowAcc[i][r];
        }
        if (kq == 0) {
#pragma unroll
            for (int j = 0; j < 4; ++j)
                cred[wr][wc * 64 + j * 16 + m] = colAcc[j];
        }
        __syncthreads();                         // sred/cred ready; stage drained
        if (wc == 0) {
            float v = sred[0][wr][lane] + sred[1][wr][lane];
            atomicAdd(&RS[I * 128 + wr * 64 + lane], v);
        } else if (I != J) {
            int col = wr * 64 + lane;
            float v = cred[0][col] + cred[1][col];
            atomicAdd(&RS[J * 128 + col], v);
        }
        u = un; k0 += 4;
    }

    // ---- group phase: blocks 512..1023 handle group unit bid-512 ----
    if (bid >= 512) {
        float* G = ws + WS_G;
        float* E = ws + WS_E;
        int g = (bid - 512) * 4 + wave;
        const float* base = Pf + (size_t)g * 4 * DIMK;
        float v[4][2];
#pragma unroll
        for (int r = 0; r < 4; ++r) {
            v[r][0] = base[r * DIMK + lane];
            v[r][1] = base[r * DIMK + 64 + lane];
        }
        float dmat[4][4];
#pragma unroll
        for (int r = 0; r < 4; ++r)
#pragma unroll
            for (int s2 = r; s2 < 4; ++s2) {
                float p = v[r][0] * v[s2][0] + v[r][1] * v[s2][1];
#pragma unroll
                for (int mm = 1; mm < 64; mm <<= 1) p += __shfl_xor(p, mm, 64);
                dmat[r][s2] = p; dmat[s2][r] = p;
            }
        if (lane == 0) {
            float distp = 0.f;
#pragma unroll
            for (int r = 0; r < 4; ++r)
#pragma unroll
                for (int s2 = r + 1; s2 < 4; ++s2)
                    distp += dmat[r][r] + dmat[s2][s2] - 2.f * dmat[r][s2];
            dred[wave] = distp;
#pragma unroll
            for (int r = 0; r < 4; ++r) {
                float Gs = 0.f, Es = 0.f;
#pragma unroll
                for (int s2 = 0; s2 < 4; ++s2) {
                    float sim = dmat[r][s2] * 10.0f;
                    float e = __expf(sim);
                    Gs += e;
                    if (sim == 1.0f) Es += e;
                }
                G[g * 4 + r] = Gs;
                E[g * 4 + r] = Es;
            }
        }
    }

    // ---- recon partial: all blocks ----
#pragma unroll
    for (int mm = 1; mm < 64; mm <<= 1) rsum += __shfl_xor(rsum, mm, 64);
    if (lane == 0) red[wave] = rsum;
    __syncthreads();
    if (threadIdx.x == 0) {
        ws[WS_RPART + bid] = red[0] + red[1] + red[2] + red[3];
        if (bid >= 512)
            ws[WS_DPART + (bid - 512)] = dred[0] + dred[1] + dred[2] + dred[3];
    }
}

// -------- k3: finalize — one 1024-thread block --------
__global__ __launch_bounds__(1024) void finalize_kernel(const float* __restrict__ ws,
                                                        float* __restrict__ out) {
    __shared__ float redc[16], redr[16], redd[16];
    const float* RS = ws + WS_RS;
    const float* G  = ws + WS_G;
    const float* E  = ws + WS_E;

    float c = 0.f;
    for (int r = threadIdx.x; r < NROWS; r += 1024) {
        float Sv = RS[r];
        c += __logf(Sv - E[r]) - __logf(G[r] - E[r]);
    }
    float rs = 0.f;
    for (int i = threadIdx.x; i < GRID; i += 1024) rs += ws[WS_RPART + i];
    float ds = 0.f;
    for (int i = threadIdx.x; i < 512; i += 1024) ds += ws[WS_DPART + i];

#pragma unroll
    for (int mm = 1; mm < 64; mm <<= 1) {
        c  += __shfl_xor(c,  mm, 64);
        rs += __shfl_xor(rs, mm, 64);
        ds += __shfl_xor(ds, mm, 64);
    }
    int wave = threadIdx.x >> 6, lane = threadIdx.x & 63;
    if (lane == 0) { redc[wave] = c; redr[wave] = rs; redd[wave] = ds; }
    __syncthreads();
    if (threadIdx.x == 0) {
        float cs = 0.f, rss = 0.f, dss = 0.f;
#pragma unroll
        for (int i = 0; i < 16; ++i) { cs += redc[i]; rss += redr[i]; dss += redd[i]; }
        float closs = cs / (float)NROWS;
        float recon = rss / (float)RECON_N;
        float dist  = dss / (float)(2048 * 6 * DIMK);
        out[0] = recon + closs + dist;
        out[1] = closs;
        out[2] = recon;
        out[3] = dist;
    }
}

extern "C" void kernel_launch(void* const* d_in, const int* in_sizes, int n_in,
                              void* d_out, int out_size, void* d_ws, size_t ws_size,
                              hipStream_t stream) {
    const float* P  = (const float*)d_in[0];    // projections 8192x128 fp32
    const float4* X = (const float4*)d_in[1];   // xrecon 8192x784 fp32
    const float4* Y = (const float4*)d_in[2];   // recon_label fp32
    float* out = (float*)d_out;                 // 4 fp32 scalars
    float* w = (float*)d_ws;
    unsigned short* Pb = (unsigned short*)(w + WS_PB);

    prep_kernel<<<1024, 256, 0, stream>>>((const float4*)P, (uint2*)Pb, w);
    fused_kernel<<<GRID, 256, 0, stream>>>(Pb, P, X, Y, w);
    finalize_kernel<<<1, 1024, 0, stream>>>(w, out);
}